// Round 1
// baseline (98.804 us; speedup 1.0000x reference)
//
#include <hip/hip_runtime.h>

// Problem constants (fixed by the reference)
constexpr int C_N   = 32;
constexpr int SD    = 64;    // STATE_DIM
constexpr int OBSD  = 512;
constexpr int TILES = 16;    // 16 rows/tile -> 256-row cap per category (24 sigma)

typedef __attribute__((ext_vector_type(8))) short bf16x8;
typedef __attribute__((ext_vector_type(4))) float f32x4;

union Frag { unsigned u[4]; bf16x8 h; };

// RNE f32 -> bf16 (scalar, returns bits)
__device__ __forceinline__ unsigned short bf_cvt(float f) {
    union { float f; unsigned u; } x; x.f = f;
    unsigned r = x.u + 0x7FFFu + ((x.u >> 16) & 1u);
    return (unsigned short)(r >> 16);
}
// RNE f32 pair -> packed 2xbf16 (a in low half, b in high half)
__device__ __forceinline__ unsigned bf_pack2(float a, float b) {
    union { float f; unsigned u; } x, y; x.f = a; y.f = b;
    unsigned ra = x.u + 0x7FFFu + ((x.u >> 16) & 1u);
    unsigned rb = y.u + 0x7FFFu + ((y.u >> 16) & 1u);
    return (ra >> 16) | (rb & 0xFFFF0000u);
}

// Load one 32-row K-chunk of B-fragments for this lane's two col strips,
// straight from f32 global in fragment order:
//   DST[j]   = W[K0 + quad*8 + j][wcol]        (strip 2w)
//   DST[8+j] = W[K0 + quad*8 + j][wcol + 16]   (strip 2w+1)
// Per load instruction the wave touches 4 x 64B segments -> coalesced.
#define LOADB(DST, WP, K0) { const float* _p = (WP) + (size_t)((K0) + quad * 8) * 256 + wcol; \
    _Pragma("unroll") for (int _j = 0; _j < 8; ++_j) { (DST)[_j] = _p[_j * 256]; (DST)[8 + _j] = _p[_j * 256 + 16]; } }

#define PACKLO(F, S) { (F).u[0] = bf_pack2((S)[0], (S)[1]);  (F).u[1] = bf_pack2((S)[2], (S)[3]); \
                       (F).u[2] = bf_pack2((S)[4], (S)[5]);  (F).u[3] = bf_pack2((S)[6], (S)[7]); }
#define PACKHI(F, S) { (F).u[0] = bf_pack2((S)[8], (S)[9]);  (F).u[1] = bf_pack2((S)[10], (S)[11]); \
                       (F).u[2] = bf_pack2((S)[12], (S)[13]); (F).u[3] = bf_pack2((S)[14], (S)[15]); }

// One block per (cat, 16-row tile). 512 threads = 8 waves; wave w owns col
// strips {2w, 2w+1}. Fully self-contained: per-block bucket scan, direct
// f32->bf16 fragment loads, no prep kernel, no workspace.
__global__ __launch_bounds__(512, 2) void fused_kernel(
    const float* __restrict__ state, const float* __restrict__ obs,
    const int* __restrict__ cat_ids,
    const float* __restrict__ obs_W, const float* __restrict__ obs_b,
    const float* __restrict__ state_W, const float* __restrict__ state_b,
    const float* __restrict__ l2_W, const float* __restrict__ l2_b,
    float* __restrict__ out) {

    const int c = blockIdx.x;
    const int tile = blockIdx.y;
    const int t = threadIdx.x;
    const int w = t >> 6, l = t & 63;
    const int ml = l & 15, quad = l >> 4;
    const int wcol = w * 32 + ml;

    __shared__ int scnt[32];
    __shared__ int sbase[33];
    __shared__ int sRows[16];
    __shared__ __align__(16) unsigned short sAs[16 * 72];    // state rows (pad 64->72)
    __shared__ __align__(16) unsigned short sAo[16 * 520];   // obs rows (pad 512->520)
    __shared__ __align__(16) unsigned short sX[16 * 520];    // x rows (pad 512->520)

    // ---- per-block bucket scan: 2048 ids = 32 chunks of 64; wave w owns
    //      chunks w+8i. Rank = stable order by row index. ----
    unsigned long long mym[4];
    #pragma unroll
    for (int i = 0; i < 4; ++i) {
        int r = t + 512 * i;                          // chunk = w + 8*i, bit = l
        unsigned long long bal = __ballot(cat_ids[r] == c);
        mym[i] = bal;
        if (l == 0) scnt[w + 8 * i] = __popcll(bal);
    }
    __syncthreads();
    if (t == 0) {
        int run = 0;
        for (int j = 0; j < 32; ++j) { sbase[j] = run; run += scnt[j]; }
        sbase[32] = run;
    }
    __syncthreads();
    const int n = sbase[32];
    const int rbase = tile * 16;
    if (rbase >= n) return;                           // dead tile: exit fast
    const int nr = min(16, n - rbase);

    // ---- issue weight preloads NOW (phase-1 fully + phase-2 ring head);
    //      their latency drains under list-build + gather. ----
    const float* pbs = state_W + (size_t)c * SD * 256;
    float r10[16], r11[16], rb0[16], rb1[16], rb2[16];
    LOADB(r10, pbs, 0)
    LOADB(r11, pbs, 32)
    LOADB(rb0, obs_W, 0)
    LOADB(rb1, obs_W, 32)
    LOADB(rb2, obs_W, 64)

    const int colb0 = wcol, colb1 = wcol + 16;
    const float bs0 = state_b[c * 256 + colb0], bs1 = state_b[c * 256 + colb1];
    const float bo0 = obs_b[colb0],             bo1 = obs_b[colb1];
    const float bl0 = l2_b[c * 256 + colb0],    bl1 = l2_b[c * 256 + colb1];

    // ---- build row list for this tile's rank window ----
    const unsigned long long ltm = (l == 0) ? 0ull : (~0ull >> (64 - l));
    #pragma unroll
    for (int i = 0; i < 4; ++i) {
        if ((mym[i] >> l) & 1ull) {
            int s = sbase[w + 8 * i] + __popcll(mym[i] & ltm) - rbase;
            if (s >= 0 && s < 16) sRows[s] = t + 512 * i;
        }
    }
    __syncthreads();

    // ---- gather rows -> LDS bf16 (coalesced float4; rows >= nr zeroed) ----
    if (t < 256) {                                    // state: 16 x 16 float4
        int i = t >> 4, c4 = t & 15;
        uint2 vv = make_uint2(0u, 0u);
        if (i < nr) {
            float4 v = ((const float4*)(state + (size_t)sRows[i] * SD))[c4];
            vv.x = bf_pack2(v.x, v.y); vv.y = bf_pack2(v.z, v.w);
        }
        *(uint2*)&sAs[i * 72 + c4 * 4] = vv;
    }
    #pragma unroll
    for (int i2 = 0; i2 < 4; ++i2) {                  // obs: 16 x 128 float4
        int f = t + 512 * i2;
        int i = f >> 7, c4 = f & 127;
        uint2 vv = make_uint2(0u, 0u);
        if (i < nr) {
            float4 v = ((const float4*)(obs + (size_t)sRows[i] * OBSD))[c4];
            vv.x = bf_pack2(v.x, v.y); vv.y = bf_pack2(v.z, v.w);
        }
        *(uint2*)&sAo[i * 520 + c4 * 4] = vv;
    }
    __syncthreads();

    // ---- phase 1: state_emb = relu(A_s x state_W[c] + b)  (K=64) ----
    {
        f32x4 acc0 = {0.f, 0.f, 0.f, 0.f}, acc1 = {0.f, 0.f, 0.f, 0.f};
        bf16x8 a0 = *(const bf16x8*)&sAs[ml * 72 + quad * 8];
        bf16x8 a1 = *(const bf16x8*)&sAs[ml * 72 + 32 + quad * 8];
        Frag f0, f1;
        PACKLO(f0, r10) PACKHI(f1, r10)
        acc0 = __builtin_amdgcn_mfma_f32_16x16x32_bf16(a0, f0.h, acc0, 0, 0, 0);
        acc1 = __builtin_amdgcn_mfma_f32_16x16x32_bf16(a0, f1.h, acc1, 0, 0, 0);
        PACKLO(f0, r11) PACKHI(f1, r11)
        acc0 = __builtin_amdgcn_mfma_f32_16x16x32_bf16(a1, f0.h, acc0, 0, 0, 0);
        acc1 = __builtin_amdgcn_mfma_f32_16x16x32_bf16(a1, f1.h, acc1, 0, 0, 0);
        #pragma unroll
        for (int r = 0; r < 4; ++r) {
            sX[(quad * 4 + r) * 520 + colb0] = bf_cvt(fmaxf(acc0[r] + bs0, 0.f));
            sX[(quad * 4 + r) * 520 + colb1] = bf_cvt(fmaxf(acc1[r] + bs1, 0.f));
        }
    }

    // ---- phase 2: obs_emb = A_o x obs_W + b  (K=512: 16 chunks, ring 3) ----
    f32x4 acc[2];
    acc[0] = (f32x4){0.f, 0.f, 0.f, 0.f};
    acc[1] = (f32x4){0.f, 0.f, 0.f, 0.f};
    {
        Frag f0, f1;
        #define P2STEP(KK, RB) { \
            bf16x8 a = *(const bf16x8*)&sAo[ml * 520 + (KK) * 32 + quad * 8]; \
            PACKLO(f0, RB) PACKHI(f1, RB) \
            if ((KK) + 3 < 16) LOADB(RB, obs_W, ((KK) + 3) * 32) \
            acc[0] = __builtin_amdgcn_mfma_f32_16x16x32_bf16(a, f0.h, acc[0], 0, 0, 0); \
            acc[1] = __builtin_amdgcn_mfma_f32_16x16x32_bf16(a, f1.h, acc[1], 0, 0, 0); }
        P2STEP(0,  rb0) P2STEP(1,  rb1) P2STEP(2,  rb2)
        P2STEP(3,  rb0) P2STEP(4,  rb1) P2STEP(5,  rb2)
        P2STEP(6,  rb0) P2STEP(7,  rb1) P2STEP(8,  rb2)
        P2STEP(9,  rb0) P2STEP(10, rb1) P2STEP(11, rb2)
        P2STEP(12, rb0) P2STEP(13, rb1) P2STEP(14, rb2)
        P2STEP(15, rb0)
        #undef P2STEP
    }

    // ---- preload phase-3 ring head BEFORE the sX barrier ----
    const float* pb3 = l2_W + (size_t)c * 512 * 256;
    LOADB(rb0, pb3, 0)
    LOADB(rb1, pb3, 32)
    LOADB(rb2, pb3, 64)
    #pragma unroll
    for (int r = 0; r < 4; ++r) {
        sX[(quad * 4 + r) * 520 + 256 + colb0] = bf_cvt(acc[0][r] + bo0);
        sX[(quad * 4 + r) * 520 + 256 + colb1] = bf_cvt(acc[1][r] + bo1);
    }
    __syncthreads();

    // ---- phase 3: out = x @ l2_W[c] + b  (K=512: 16 chunks, ring 3) ----
    acc[0] = (f32x4){0.f, 0.f, 0.f, 0.f};
    acc[1] = (f32x4){0.f, 0.f, 0.f, 0.f};
    {
        Frag f0, f1;
        #define P3STEP(KK, RB) { \
            bf16x8 a = *(const bf16x8*)&sX[ml * 520 + (KK) * 32 + quad * 8]; \
            PACKLO(f0, RB) PACKHI(f1, RB) \
            if ((KK) + 3 < 16) LOADB(RB, pb3, ((KK) + 3) * 32) \
            acc[0] = __builtin_amdgcn_mfma_f32_16x16x32_bf16(a, f0.h, acc[0], 0, 0, 0); \
            acc[1] = __builtin_amdgcn_mfma_f32_16x16x32_bf16(a, f1.h, acc[1], 0, 0, 0); }
        P3STEP(0,  rb0) P3STEP(1,  rb1) P3STEP(2,  rb2)
        P3STEP(3,  rb0) P3STEP(4,  rb1) P3STEP(5,  rb2)
        P3STEP(6,  rb0) P3STEP(7,  rb1) P3STEP(8,  rb2)
        P3STEP(9,  rb0) P3STEP(10, rb1) P3STEP(11, rb2)
        P3STEP(12, rb0) P3STEP(13, rb1) P3STEP(14, rb2)
        P3STEP(15, rb0)
        #undef P3STEP
    }
    #pragma unroll
    for (int r = 0; r < 4; ++r) {
        int row = quad * 4 + r;
        if (row < nr) {
            float* orow = out + (size_t)sRows[row] * 256;
            orow[colb0] = acc[0][r] + bl0;
            orow[colb1] = acc[1][r] + bl1;
        }
    }
}

extern "C" void kernel_launch(void* const* d_in, const int* in_sizes, int n_in,
                              void* d_out, int out_size, void* d_ws, size_t ws_size,
                              hipStream_t stream) {
    (void)in_sizes; (void)n_in; (void)out_size; (void)d_ws; (void)ws_size;
    fused_kernel<<<dim3(C_N, TILES), dim3(512), 0, stream>>>(
        (const float*)d_in[0],   // state
        (const float*)d_in[1],   // obs
        (const int*)d_in[2],     // cat_ids
        (const float*)d_in[3],   // obs_W
        (const float*)d_in[4],   // obs_b
        (const float*)d_in[5],   // state_W
        (const float*)d_in[6],   // state_b
        (const float*)d_in[7],   // l2_W
        (const float*)d_in[8],   // l2_b
        (float*)d_out);
}

// Round 2
// 96.559 us; speedup vs baseline: 1.0232x; 1.0232x over previous
//
#include <hip/hip_runtime.h>

// Problem constants (fixed by the reference)
constexpr int C_N   = 32;
constexpr int SD    = 64;    // STATE_DIM
constexpr int OBSD  = 512;
constexpr int TILES = 16;    // 16 rows/tile -> 256-row cap per category (24 sigma)

typedef __attribute__((ext_vector_type(8))) short bf16x8;
typedef __attribute__((ext_vector_type(4))) float f32x4;

union Frag { unsigned u[4]; bf16x8 h; };

// Hardware RNE: pack 2 f32 -> 2 bf16 in one VALU op (lo in low half).
__device__ __forceinline__ unsigned cvt_pk2(float lo, float hi) {
    unsigned r;
    asm("v_cvt_pk_bf16_f32 %0, %1, %2" : "=v"(r) : "v"(lo), "v"(hi));
    return r;
}
__device__ __forceinline__ unsigned short cvt1(float f) {
    return (unsigned short)cvt_pk2(f, f);
}

// Load one 32-row K-chunk of B-fragments for this lane's two col strips,
// straight from f32 global in fragment order:
//   DST[j]   = W[K0 + quad*8 + j][wcol]        (strip 2w)
//   DST[8+j] = W[K0 + quad*8 + j][wcol + 16]   (strip 2w+1)
// Per load instruction the wave touches 4 x 64B fully-used segments.
#define LOADB(DST, WP, K0) { const float* _p = (WP) + (size_t)((K0) + quad * 8) * 256 + wcol; \
    _Pragma("unroll") for (int _j = 0; _j < 8; ++_j) { (DST)[_j] = _p[_j * 256]; (DST)[8 + _j] = _p[_j * 256 + 16]; } }

#define PACKLO(F, S) { (F).u[0] = cvt_pk2((S)[0], (S)[1]);  (F).u[1] = cvt_pk2((S)[2], (S)[3]); \
                       (F).u[2] = cvt_pk2((S)[4], (S)[5]);  (F).u[3] = cvt_pk2((S)[6], (S)[7]); }
#define PACKHI(F, S) { (F).u[0] = cvt_pk2((S)[8], (S)[9]);  (F).u[1] = cvt_pk2((S)[10], (S)[11]); \
                       (F).u[2] = cvt_pk2((S)[12], (S)[13]); (F).u[3] = cvt_pk2((S)[14], (S)[15]); }

// One block per (cat, 16-row tile). 512 threads = 8 waves; wave w owns col
// strips {2w, 2w+1}. Fully self-contained: per-block bucket scan, direct
// f32->bf16 fragment loads (hardware cvt_pk), no prep kernel, no workspace.
__global__ __launch_bounds__(512, 1) void fused_kernel(
    const float* __restrict__ state, const float* __restrict__ obs,
    const int* __restrict__ cat_ids,
    const float* __restrict__ obs_W, const float* __restrict__ obs_b,
    const float* __restrict__ state_W, const float* __restrict__ state_b,
    const float* __restrict__ l2_W, const float* __restrict__ l2_b,
    float* __restrict__ out) {

    const int c = blockIdx.x;
    const int tile = blockIdx.y;
    const int t = threadIdx.x;
    const int w = t >> 6, l = t & 63;
    const int ml = l & 15, quad = l >> 4;
    const int wcol = w * 32 + ml;

    __shared__ int scnt[32];
    __shared__ int sbase[33];
    __shared__ int sRows[16];
    __shared__ __align__(16) unsigned short sAs[16 * 72];    // state rows (pad 64->72)
    __shared__ __align__(16) unsigned short sAo[16 * 520];   // obs rows (pad 512->520)
    __shared__ __align__(16) unsigned short sX[16 * 520];    // x rows (pad 512->520)

    // ---- bias loads first: latency drains under the bucket scan ----
    const int colb0 = wcol, colb1 = wcol + 16;
    const float bs0 = state_b[c * 256 + colb0], bs1 = state_b[c * 256 + colb1];
    const float bo0 = obs_b[colb0],             bo1 = obs_b[colb1];
    const float bl0 = l2_b[c * 256 + colb0],    bl1 = l2_b[c * 256 + colb1];

    // ---- per-block bucket scan: 2048 ids = 32 chunks of 64; wave w owns
    //      chunks w+8i. Rank = stable order by row index. ----
    unsigned long long mym[4];
    #pragma unroll
    for (int i = 0; i < 4; ++i) {
        int r = t + 512 * i;                          // chunk = w + 8*i, bit = l
        unsigned long long bal = __ballot(cat_ids[r] == c);
        mym[i] = bal;
        if (l == 0) scnt[w + 8 * i] = __popcll(bal);
    }
    __syncthreads();
    if (t < 64) {       // wave-parallel exclusive prefix over the 32 counts
        int v = (l < 32) ? scnt[l] : 0;
        #pragma unroll
        for (int d = 1; d < 32; d <<= 1) {
            int o = __shfl_up(v, d, 64);
            if (l >= d) v += o;
        }
        if (l < 32) sbase[l + 1] = v;
        if (l == 0) sbase[0] = 0;
    }
    __syncthreads();
    const int n = sbase[32];
    const int rbase = tile * 16;
    if (rbase >= n) return;                           // dead tile: exit fast
    const int nr = min(16, n - rbase);

    // ---- issue weight preloads NOW (phase-1 fully + phase-2 ring head);
    //      their latency drains under list-build + gather. ----
    const float* pbs = state_W + (size_t)c * SD * 256;
    float r10[16], r11[16], rb0[16], rb1[16], rb2[16], rb3[16];
    LOADB(r10, pbs, 0)
    LOADB(r11, pbs, 32)
    LOADB(rb0, obs_W, 0)
    LOADB(rb1, obs_W, 32)

    // ---- build row list for this tile's rank window ----
    const unsigned long long ltm = (l == 0) ? 0ull : (~0ull >> (64 - l));
    #pragma unroll
    for (int i = 0; i < 4; ++i) {
        if ((mym[i] >> l) & 1ull) {
            int s = sbase[w + 8 * i] + __popcll(mym[i] & ltm) - rbase;
            if (s >= 0 && s < 16) sRows[s] = t + 512 * i;
        }
    }
    __syncthreads();

    // ---- gather rows -> LDS bf16 (coalesced float4; rows >= nr zeroed) ----
    if (t < 256) {                                    // state: 16 x 16 float4
        int i = t >> 4, c4 = t & 15;
        uint2 vv = make_uint2(0u, 0u);
        if (i < nr) {
            float4 v = ((const float4*)(state + (size_t)sRows[i] * SD))[c4];
            vv.x = cvt_pk2(v.x, v.y); vv.y = cvt_pk2(v.z, v.w);
        }
        *(uint2*)&sAs[i * 72 + c4 * 4] = vv;
    }
    #pragma unroll
    for (int i2 = 0; i2 < 4; ++i2) {                  // obs: 16 x 128 float4
        int f = t + 512 * i2;
        int i = f >> 7, c4 = f & 127;
        uint2 vv = make_uint2(0u, 0u);
        if (i < nr) {
            float4 v = ((const float4*)(obs + (size_t)sRows[i] * OBSD))[c4];
            vv.x = cvt_pk2(v.x, v.y); vv.y = cvt_pk2(v.z, v.w);
        }
        *(uint2*)&sAo[i * 520 + c4 * 4] = vv;
    }
    // rest of the phase-2 ring head (issue after gather loads are in flight)
    LOADB(rb2, obs_W, 64)
    LOADB(rb3, obs_W, 96)
    __syncthreads();

    // ---- phase 1: state_emb = relu(A_s x state_W[c] + b)  (K=64) ----
    {
        f32x4 acc0 = {0.f, 0.f, 0.f, 0.f}, acc1 = {0.f, 0.f, 0.f, 0.f};
        bf16x8 a0 = *(const bf16x8*)&sAs[ml * 72 + quad * 8];
        bf16x8 a1 = *(const bf16x8*)&sAs[ml * 72 + 32 + quad * 8];
        Frag f0, f1;
        PACKLO(f0, r10) PACKHI(f1, r10)
        acc0 = __builtin_amdgcn_mfma_f32_16x16x32_bf16(a0, f0.h, acc0, 0, 0, 0);
        acc1 = __builtin_amdgcn_mfma_f32_16x16x32_bf16(a0, f1.h, acc1, 0, 0, 0);
        PACKLO(f0, r11) PACKHI(f1, r11)
        acc0 = __builtin_amdgcn_mfma_f32_16x16x32_bf16(a1, f0.h, acc0, 0, 0, 0);
        acc1 = __builtin_amdgcn_mfma_f32_16x16x32_bf16(a1, f1.h, acc1, 0, 0, 0);
        #pragma unroll
        for (int r = 0; r < 4; ++r) {
            sX[(quad * 4 + r) * 520 + colb0] = cvt1(fmaxf(acc0[r] + bs0, 0.f));
            sX[(quad * 4 + r) * 520 + colb1] = cvt1(fmaxf(acc1[r] + bs1, 0.f));
        }
    }

    // ---- phase 2: obs_emb = A_o x obs_W + b  (K=512: 16 chunks, ring 4) ----
    f32x4 acc[2];
    acc[0] = (f32x4){0.f, 0.f, 0.f, 0.f};
    acc[1] = (f32x4){0.f, 0.f, 0.f, 0.f};
    {
        Frag f0, f1;
        #define P2STEP(KK, RB) { \
            bf16x8 a = *(const bf16x8*)&sAo[ml * 520 + (KK) * 32 + quad * 8]; \
            PACKLO(f0, RB) PACKHI(f1, RB) \
            if ((KK) + 4 < 16) LOADB(RB, obs_W, ((KK) + 4) * 32) \
            acc[0] = __builtin_amdgcn_mfma_f32_16x16x32_bf16(a, f0.h, acc[0], 0, 0, 0); \
            acc[1] = __builtin_amdgcn_mfma_f32_16x16x32_bf16(a, f1.h, acc[1], 0, 0, 0); }
        P2STEP(0,  rb0) P2STEP(1,  rb1) P2STEP(2,  rb2) P2STEP(3,  rb3)
        P2STEP(4,  rb0) P2STEP(5,  rb1) P2STEP(6,  rb2) P2STEP(7,  rb3)
        P2STEP(8,  rb0) P2STEP(9,  rb1) P2STEP(10, rb2) P2STEP(11, rb3)
        P2STEP(12, rb0) P2STEP(13, rb1) P2STEP(14, rb2) P2STEP(15, rb3)
        #undef P2STEP
    }

    // ---- preload phase-3 ring head BEFORE the sX barrier ----
    const float* pb3 = l2_W + (size_t)c * 512 * 256;
    LOADB(rb0, pb3, 0)
    LOADB(rb1, pb3, 32)
    LOADB(rb2, pb3, 64)
    LOADB(rb3, pb3, 96)
    #pragma unroll
    for (int r = 0; r < 4; ++r) {
        sX[(quad * 4 + r) * 520 + 256 + colb0] = cvt1(acc[0][r] + bo0);
        sX[(quad * 4 + r) * 520 + 256 + colb1] = cvt1(acc[1][r] + bo1);
    }
    __syncthreads();

    // ---- phase 3: out = x @ l2_W[c] + b  (K=512: 16 chunks, ring 4) ----
    acc[0] = (f32x4){0.f, 0.f, 0.f, 0.f};
    acc[1] = (f32x4){0.f, 0.f, 0.f, 0.f};
    {
        Frag f0, f1;
        #define P3STEP(KK, RB) { \
            bf16x8 a = *(const bf16x8*)&sX[ml * 520 + (KK) * 32 + quad * 8]; \
            PACKLO(f0, RB) PACKHI(f1, RB) \
            if ((KK) + 4 < 16) LOADB(RB, pb3, ((KK) + 4) * 32) \
            acc[0] = __builtin_amdgcn_mfma_f32_16x16x32_bf16(a, f0.h, acc[0], 0, 0, 0); \
            acc[1] = __builtin_amdgcn_mfma_f32_16x16x32_bf16(a, f1.h, acc[1], 0, 0, 0); }
        P3STEP(0,  rb0) P3STEP(1,  rb1) P3STEP(2,  rb2) P3STEP(3,  rb3)
        P3STEP(4,  rb0) P3STEP(5,  rb1) P3STEP(6,  rb2) P3STEP(7,  rb3)
        P3STEP(8,  rb0) P3STEP(9,  rb1) P3STEP(10, rb2) P3STEP(11, rb3)
        P3STEP(12, rb0) P3STEP(13, rb1) P3STEP(14, rb2) P3STEP(15, rb3)
        #undef P3STEP
    }
    #pragma unroll
    for (int r = 0; r < 4; ++r) {
        int row = quad * 4 + r;
        if (row < nr) {
            float* orow = out + (size_t)sRows[row] * 256;
            orow[colb0] = acc[0][r] + bl0;
            orow[colb1] = acc[1][r] + bl1;
        }
    }
}

extern "C" void kernel_launch(void* const* d_in, const int* in_sizes, int n_in,
                              void* d_out, int out_size, void* d_ws, size_t ws_size,
                              hipStream_t stream) {
    (void)in_sizes; (void)n_in; (void)out_size; (void)d_ws; (void)ws_size;
    fused_kernel<<<dim3(C_N, TILES), dim3(512), 0, stream>>>(
        (const float*)d_in[0],   // state
        (const float*)d_in[1],   // obs
        (const int*)d_in[2],     // cat_ids
        (const float*)d_in[3],   // obs_W
        (const float*)d_in[4],   // obs_b
        (const float*)d_in[5],   // state_W
        (const float*)d_in[6],   // state_b
        (const float*)d_in[7],   // l2_W
        (const float*)d_in[8],   // l2_b
        (float*)d_out);
}